// Round 5
// baseline (914.539 us; speedup 1.0000x reference)
//
#include <hip/hip_runtime.h>
#include <stdint.h>

// SmallMLP_INR: fused 6-layer MLP (2->256->256x4->1, ReLU) over 524288 points.
// Split-bf16 MFMA (x = hi + lo truncate-split): 3 products Wh*Xh + Wl*Xh + Wh*Xl,
// fp32 accum (measured absmax 6.1e-5 vs 1.99e-4 threshold; error dominated by
// 17-bit activation storage — f16/i8 schemes fail the calibrated error model).
// R5: anti-phase-lock. R1-R4 walls (720-840 us) all exceed every pipe's busy sum;
// the 2 co-resident 4-wave blocks were barrier-phase-locked so stalls ADD. Now:
// MT=32, 128-thread (2-wave) blocks, 32 KB LDS -> 4 INDEPENDENT blocks/CU. Each
// wave owns 128 n_out (4 tiles of 32): 12 MFMA : 2 LDS-reads per ks (R4 was 12:4).
// Known cost: weight L2 traffic doubles (~58% of L2 ceiling) — deliberate trade.

#define WIDTH 256
#define MT 32
#define WPLANE (4 * 65536)   // ushorts per packed weight plane (4 layers)

typedef short short8 __attribute__((ext_vector_type(8)));
typedef float f32x16 __attribute__((ext_vector_type(16)));
typedef float float4v __attribute__((ext_vector_type(4)));

// truncate-split f32 -> bf16 hi + bf16 lo (lo also truncated; total ~17 bits)
__device__ __forceinline__ void split_bf(float f, unsigned short &hi, unsigned short &lo) {
    union { float f; uint32_t u; } a; a.f = f;
    hi = (unsigned short)(a.u >> 16);
    union { uint32_t u; float f; } h; h.u = a.u & 0xffff0000u;
    union { float f; uint32_t u; } d; d.f = f - h.f;   // exact (Sterbenz)
    lo = (unsigned short)(d.u >> 16);
}

__device__ __forceinline__ float bf2f(unsigned short h) {
    union { uint32_t u; float f; } a; a.u = ((uint32_t)h) << 16; return a.f;
}

// LDS activation addressing: X[point][feat], row stride 256 ushorts, 16B-chunk
// index XOR-swizzled by (point&7).
__device__ __forceinline__ int xaddr(int m, int n) {
    int c = n >> 3;
    return m * 256 + (((c ^ (m & 7)) << 3) | (n & 7));
}

// Pack W2..W5 (256x256 row-major [k][n]) into 32x32x16 A-fragment order for the
// TRANSPOSED product (A = W^T): element = W[k][n_out],
//   n_out = 32*t + (lane&31), k = 16*ks + 8*(lane>>5) + j, t = n_out tile 0..7.
// Linear index: (((l*8 + t)*16 + ks)*64 + lane)*8 + j.   [verified R3/R4]
__global__ void prep_weights(const float* __restrict__ W2, const float* __restrict__ W3,
                             const float* __restrict__ W4, const float* __restrict__ W5,
                             unsigned short* __restrict__ whi, unsigned short* __restrict__ wlo) {
    int tid = blockIdx.x * 256 + threadIdx.x;   // 262144 total
    int j    = tid & 7;
    int lane = (tid >> 3) & 63;
    int ks   = (tid >> 9) & 15;
    int t    = (tid >> 13) & 7;
    int l    = tid >> 16;
    int n_out = 32 * t + (lane & 31);
    int k     = 16 * ks + 8 * (lane >> 5) + j;
    const float* W = (l == 0) ? W2 : (l == 1) ? W3 : (l == 2) ? W4 : W5;
    float w = W[k * 256 + n_out];
    unsigned short hi, lo;
    split_bf(w, hi, lo);
    whi[tid] = hi;
    wlo[tid] = lo;
}

__global__ __launch_bounds__(128, 2) void mlp_fused(
    const float* __restrict__ coords,
    const float* __restrict__ W1, const float* __restrict__ b1,
    const float* __restrict__ b2, const float* __restrict__ b3,
    const float* __restrict__ b4, const float* __restrict__ b5,
    const float* __restrict__ W6, const float* __restrict__ b6,
    const unsigned short* __restrict__ whi, const unsigned short* __restrict__ wlo,
    float* __restrict__ out)
{
    __shared__ unsigned short Xhi[32 * 256];   // 16 KB
    __shared__ unsigned short Xlo[32 * 256];   // 16 KB (total 32 KB -> 4 blocks/CU)

    const int tid = threadIdx.x;
    const int m0 = blockIdx.x * MT;

    // ---- layer 1: 2 -> 256 (VALU). Thread owns features tid and tid+128. ----
    {
        const int n1 = tid, n2 = tid + 128;
        const float w0a = W1[n1], w1a = W1[WIDTH + n1], ba = b1[n1];
        const float w0b = W1[n2], w1b = W1[WIDTH + n2], bb = b1[n2];
        for (int m = 0; m < MT; ++m) {
            float c0 = coords[(m0 + m) * 2];   // uniform across lanes
            float c1 = coords[(m0 + m) * 2 + 1];
            float va = fmaxf(fmaf(c0, w0a, fmaf(c1, w1a, ba)), 0.0f);
            float vb = fmaxf(fmaf(c0, w0b, fmaf(c1, w1b, bb)), 0.0f);
            unsigned short h, l;
            split_bf(va, h, l);
            int a = xaddr(m, n1);
            Xhi[a] = h; Xlo[a] = l;
            split_bf(vb, h, l);
            a = xaddr(m, n2);
            Xhi[a] = h; Xlo[a] = l;
        }
    }
    __syncthreads();

    const int hw   = tid >> 6;     // wave 0..1 owns output features [128*hw, +128)
    const int lane = tid & 63;
    const int l31  = lane & 31;
    const int lh   = lane >> 5;    // k-half selector

    // ---- layers 2..5: 256 -> 256 via 32x32x16 bf16 MFMA, swapped operands.
    // C^T[n_out][point] = sum_k W[k][n_out] * X[point][k].
    for (int l = 0; l < 4; ++l) {
        const float* bias = (l == 0) ? b2 : (l == 1) ? b3 : (l == 2) ? b4 : b5;

        // bias folded into acc init: D row n_out = base + (reg&3) + 8*(reg>>2) + 4*lh
        f32x16 acc[4];
        #pragma unroll
        for (int nt = 0; nt < 4; ++nt)
            #pragma unroll
            for (int r4 = 0; r4 < 4; ++r4) {
                const float4v bv = *(const float4v*)(bias + 128 * hw + 32 * nt + 8 * r4 + 4 * lh);
                #pragma unroll
                for (int q = 0; q < 4; ++q)
                    acc[nt][4 * r4 + q] = bv[q];
            }

        // weight A-frag bases for the wave's four 32-wide n_out tiles
        const unsigned short* wbh[4];
        const unsigned short* wbl[4];
        #pragma unroll
        for (int nt = 0; nt < 4; ++nt) {
            const int t = 4 * hw + nt;
            wbh[nt] = whi + (((l * 8 + t) * 16) * 64 + lane) * 8;
            wbl[nt] = wlo + (((l * 8 + t) * 16) * 64 + lane) * 8;
        }

        #pragma unroll 4
        for (int ks = 0; ks < 16; ++ks) {
            // A-frags (weights) from L2, lane-contiguous 16B
            short8 wh[4], wl[4];
            #pragma unroll
            for (int nt = 0; nt < 4; ++nt) {
                wh[nt] = *(const short8*)(wbh[nt] + ks * 512);
                wl[nt] = *(const short8*)(wbl[nt] + ks * 512);
            }
            // B-frags (X) from LDS: single point-tile -> only 2 reads per ks
            const int ko = 16 * ks + 8 * lh;
            const int a0 = xaddr(l31, ko);
            const short8 xh = *(const short8*)(Xhi + a0);
            const short8 xl = *(const short8*)(Xlo + a0);

            // 12 MFMAs, same-acc reuse distance 4 (~128 cyc)
            #pragma unroll
            for (int nt = 0; nt < 4; ++nt)
                acc[nt] = __builtin_amdgcn_mfma_f32_32x32x16_bf16(wh[nt], xh, acc[nt], 0, 0, 0);
            #pragma unroll
            for (int nt = 0; nt < 4; ++nt)
                acc[nt] = __builtin_amdgcn_mfma_f32_32x32x16_bf16(wl[nt], xh, acc[nt], 0, 0, 0);
            #pragma unroll
            for (int nt = 0; nt < 4; ++nt)
                acc[nt] = __builtin_amdgcn_mfma_f32_32x32x16_bf16(wh[nt], xl, acc[nt], 0, 0, 0);
        }
        __syncthreads();   // both waves done reading X before overwrite (2-wave barrier)

        // epilogue: ReLU + re-split + aligned b64 stores.
        // Lane holds point p = l31, n_out in 4-runs: 128hw + 32nt + 8r4 + 4lh
        #pragma unroll
        for (int nt = 0; nt < 4; ++nt) {
            #pragma unroll
            for (int r4 = 0; r4 < 4; ++r4) {
                unsigned short h[4], lo2[4];
                #pragma unroll
                for (int q = 0; q < 4; ++q) {
                    float v = fmaxf(acc[nt][4 * r4 + q], 0.0f);
                    split_bf(v, h[q], lo2[q]);
                }
                const int nb = 128 * hw + 32 * nt + 8 * r4 + 4 * lh;
                const int a = xaddr(l31, nb);   // 8B aligned within one 16B chunk
                uint2 ph, pl;
                ph.x = (uint32_t)h[0] | ((uint32_t)h[1] << 16);
                ph.y = (uint32_t)h[2] | ((uint32_t)h[3] << 16);
                pl.x = (uint32_t)lo2[0] | ((uint32_t)lo2[1] << 16);
                pl.y = (uint32_t)lo2[2] | ((uint32_t)lo2[3] << 16);
                *(uint2*)(Xhi + a) = ph;
                *(uint2*)(Xlo + a) = pl;
            }
        }
        __syncthreads();
    }

    // ---- layer 6: 256 -> 1 (VALU). 4 threads per point, shuffle-reduce. ----
    {
        const int m = tid >> 2;        // 0..31
        const int cq = tid & 3;
        float s = 0.0f;
        #pragma unroll
        for (int g = 0; g < 8; ++g) {
            int nb = cq * 64 + g * 8;
            int a = xaddr(m, nb);
            const short8 hv = *(const short8*)(Xhi + a);
            const short8 lv = *(const short8*)(Xlo + a);
            const float* wp = W6 + nb;
            #pragma unroll
            for (int j = 0; j < 8; ++j) {
                float x = bf2f((unsigned short)hv[j]) + bf2f((unsigned short)lv[j]);
                s = fmaf(x, wp[j], s);
            }
        }
        s += __shfl_xor(s, 1);
        s += __shfl_xor(s, 2);
        if (cq == 0) out[m0 + m] = s + b6[0];
    }
}

extern "C" void kernel_launch(void* const* d_in, const int* in_sizes, int n_in,
                              void* d_out, int out_size, void* d_ws, size_t ws_size,
                              hipStream_t stream) {
    const float* coords = (const float*)d_in[0];
    const float* W1 = (const float*)d_in[1];
    const float* b1 = (const float*)d_in[2];
    const float* W2 = (const float*)d_in[3];
    const float* b2 = (const float*)d_in[4];
    const float* W3 = (const float*)d_in[5];
    const float* b3 = (const float*)d_in[6];
    const float* W4 = (const float*)d_in[7];
    const float* b4 = (const float*)d_in[8];
    const float* W5 = (const float*)d_in[9];
    const float* b5 = (const float*)d_in[10];
    const float* W6 = (const float*)d_in[11];
    const float* b6 = (const float*)d_in[12];
    float* out = (float*)d_out;

    unsigned short* whi = (unsigned short*)d_ws;    // 512 KB
    unsigned short* wlo = whi + WPLANE;             // 512 KB (ws total 1 MB)

    prep_weights<<<1024, 256, 0, stream>>>(W2, W3, W4, W5, whi, wlo);

    const int nblocks = out_size / MT;              // 16384
    mlp_fused<<<nblocks, 128, 0, stream>>>(coords, W1, b1, b2, b3, b4, b5,
                                           W6, b6, whi, wlo, out);
}

// Round 6
// 727.774 us; speedup vs baseline: 1.2566x; 1.2566x over previous
//
#include <hip/hip_runtime.h>
#include <stdint.h>

// SmallMLP_INR: fused 6-layer MLP (2->256->256x4->1, ReLU) over 524288 points.
// Split-bf16 MFMA (x = hi + lo truncate-split): 3 products Wh*Xh + Wl*Xh + Wh*Xl,
// fp32 accum (measured absmax 6.1e-5 vs 1.99e-4 threshold).
// R6: R4 structure + explicit software-pipelined K-loop. R1-R5 invariant: MFMA
// busy is always ~370-390 us (the floor); the wall is L2 weight-load LATENCY
// (~200-400 cyc) unhidden at 2 waves/SIMD — R4's K-iter measured ~1560 cyc vs
// 384 cyc MFMA issue. Fix: weight frags prefetched distance-2 (4-slot ring,
// ~768 cyc slack), X frags distance-1 (LDS ~120 cyc). Full unroll -> ring
// indices are compile-time; loads are register-destined, no barrier in loop.

#define WIDTH 256
#define MT 64
#define WPLANE (4 * 65536)   // ushorts per packed weight plane (4 layers)

typedef short short8 __attribute__((ext_vector_type(8)));
typedef float f32x16 __attribute__((ext_vector_type(16)));
typedef float float4v __attribute__((ext_vector_type(4)));

// truncate-split f32 -> bf16 hi + bf16 lo (lo also truncated; total ~17 bits)
__device__ __forceinline__ void split_bf(float f, unsigned short &hi, unsigned short &lo) {
    union { float f; uint32_t u; } a; a.f = f;
    hi = (unsigned short)(a.u >> 16);
    union { uint32_t u; float f; } h; h.u = a.u & 0xffff0000u;
    union { float f; uint32_t u; } d; d.f = f - h.f;   // exact (Sterbenz)
    lo = (unsigned short)(d.u >> 16);
}

__device__ __forceinline__ float bf2f(unsigned short h) {
    union { uint32_t u; float f; } a; a.u = ((uint32_t)h) << 16; return a.f;
}

// LDS activation addressing: X[point][feat], row stride 256 ushorts, 16B-chunk
// index XOR-swizzled by (point&7).
__device__ __forceinline__ int xaddr(int m, int n) {
    int c = n >> 3;
    return m * 256 + (((c ^ (m & 7)) << 3) | (n & 7));
}

// Pack W2..W5 (256x256 row-major [k][n]) into 32x32x16 A-fragment order for the
// TRANSPOSED product (A = W^T): element = W[k][n_out],
//   n_out = 32*t + (lane&31), k = 16*ks + 8*(lane>>5) + j, t = n_out tile 0..7.
// Linear index: (((l*8 + t)*16 + ks)*64 + lane)*8 + j.   [verified R3/R4/R5]
__global__ void prep_weights(const float* __restrict__ W2, const float* __restrict__ W3,
                             const float* __restrict__ W4, const float* __restrict__ W5,
                             unsigned short* __restrict__ whi, unsigned short* __restrict__ wlo) {
    int tid = blockIdx.x * 256 + threadIdx.x;   // 262144 total
    int j    = tid & 7;
    int lane = (tid >> 3) & 63;
    int ks   = (tid >> 9) & 15;
    int t    = (tid >> 13) & 7;
    int l    = tid >> 16;
    int n_out = 32 * t + (lane & 31);
    int k     = 16 * ks + 8 * (lane >> 5) + j;
    const float* W = (l == 0) ? W2 : (l == 1) ? W3 : (l == 2) ? W4 : W5;
    float w = W[k * 256 + n_out];
    unsigned short hi, lo;
    split_bf(w, hi, lo);
    whi[tid] = hi;
    wlo[tid] = lo;
}

__global__ __launch_bounds__(256, 2) void mlp_fused(
    const float* __restrict__ coords,
    const float* __restrict__ W1, const float* __restrict__ b1,
    const float* __restrict__ b2, const float* __restrict__ b3,
    const float* __restrict__ b4, const float* __restrict__ b5,
    const float* __restrict__ W6, const float* __restrict__ b6,
    const unsigned short* __restrict__ whi, const unsigned short* __restrict__ wlo,
    float* __restrict__ out)
{
    __shared__ unsigned short Xhi[64 * 256];   // 32 KB
    __shared__ unsigned short Xlo[64 * 256];   // 32 KB  (total 64 KB -> 2 blocks/CU)

    const int tid = threadIdx.x;
    const int m0 = blockIdx.x * MT;

    // ---- layer 1: 2 -> 256 (VALU). Thread owns feature n = tid. ----
    {
        const float w0 = W1[tid];
        const float w1 = W1[WIDTH + tid];
        const float bb = b1[tid];
        for (int m = 0; m < MT; ++m) {
            float c0 = coords[(m0 + m) * 2];   // uniform across lanes -> s_load
            float c1 = coords[(m0 + m) * 2 + 1];
            float v = fmaf(c0, w0, fmaf(c1, w1, bb));
            v = fmaxf(v, 0.0f);
            unsigned short h, l;
            split_bf(v, h, l);
            int a = xaddr(m, tid);
            Xhi[a] = h;
            Xlo[a] = l;
        }
    }
    __syncthreads();

    const int wv   = tid >> 6;     // wave 0..3 owns output features [64*wv, +64)
    const int lane = tid & 63;
    const int l31  = lane & 31;
    const int lh   = lane >> 5;    // k-half selector

    // ---- layers 2..5: 256 -> 256 via 32x32x16 bf16 MFMA, swapped operands.
    // C^T[n_out][point] = sum_k W[k][n_out] * X[point][k].
    for (int l = 0; l < 4; ++l) {
        const float* bias = (l == 0) ? b2 : (l == 1) ? b3 : (l == 2) ? b4 : b5;

        // bias folded into acc init: D row n_out = base + (reg&3) + 8*(reg>>2) + 4*lh
        f32x16 acc00, acc01, acc10, acc11;
        #pragma unroll
        for (int r4 = 0; r4 < 4; ++r4) {
            const float4v bv0 = *(const float4v*)(bias + 64 * wv + 8 * r4 + 4 * lh);
            const float4v bv1 = *(const float4v*)(bias + 64 * wv + 32 + 8 * r4 + 4 * lh);
            #pragma unroll
            for (int q = 0; q < 4; ++q) {
                acc00[4 * r4 + q] = bv0[q];
                acc01[4 * r4 + q] = bv0[q];
                acc10[4 * r4 + q] = bv1[q];
                acc11[4 * r4 + q] = bv1[q];
            }
        }

        // weight A-frag bases for the wave's two 32-wide n_out tiles
        const int t0 = 2 * wv, t1 = 2 * wv + 1;
        const unsigned short* wh0 = whi + (((l * 8 + t0) * 16) * 64 + lane) * 8;
        const unsigned short* wl0 = wlo + (((l * 8 + t0) * 16) * 64 + lane) * 8;
        const unsigned short* wh1 = whi + (((l * 8 + t1) * 16) * 64 + lane) * 8;
        const unsigned short* wl1 = wlo + (((l * 8 + t1) * 16) * 64 + lane) * 8;

        // ---- software-pipelined K-loop: weights prefetch distance 2 (ring of
        // 4), X prefetch distance 1 (ring of 2). Fully unrolled.
        short8 qh0[4], ql0[4], qh1[4], ql1[4];     // weight rings
        short8 pxh0[2], pxh1[2], pxl0[2], pxl1[2]; // X rings

        #pragma unroll
        for (int p = 0; p < 2; ++p) {
            qh0[p] = *(const short8*)(wh0 + p * 512);
            ql0[p] = *(const short8*)(wl0 + p * 512);
            qh1[p] = *(const short8*)(wh1 + p * 512);
            ql1[p] = *(const short8*)(wl1 + p * 512);
        }
        {
            const int ko = 8 * lh;
            const int a0 = xaddr(l31,      ko);
            const int a1 = xaddr(32 + l31, ko);
            pxh0[0] = *(const short8*)(Xhi + a0);
            pxh1[0] = *(const short8*)(Xhi + a1);
            pxl0[0] = *(const short8*)(Xlo + a0);
            pxl1[0] = *(const short8*)(Xlo + a1);
        }

        #pragma unroll
        for (int ks = 0; ks < 16; ++ks) {
            const int s  = ks & 3;
            const int sn = (ks + 2) & 3;
            const int xs = ks & 1;
            const int xn = (ks + 1) & 1;
            if (ks < 14) {   // compile-time after unroll
                qh0[sn] = *(const short8*)(wh0 + (ks + 2) * 512);
                ql0[sn] = *(const short8*)(wl0 + (ks + 2) * 512);
                qh1[sn] = *(const short8*)(wh1 + (ks + 2) * 512);
                ql1[sn] = *(const short8*)(wl1 + (ks + 2) * 512);
            }
            if (ks < 15) {
                const int ko = 16 * (ks + 1) + 8 * lh;
                const int a0 = xaddr(l31,      ko);
                const int a1 = xaddr(32 + l31, ko);
                pxh0[xn] = *(const short8*)(Xhi + a0);
                pxh1[xn] = *(const short8*)(Xhi + a1);
                pxl0[xn] = *(const short8*)(Xlo + a0);
                pxl1[xn] = *(const short8*)(Xlo + a1);
            }
            // 12 MFMAs on the CURRENT slots; same-acc reuse distance 4
            acc00 = __builtin_amdgcn_mfma_f32_32x32x16_bf16(qh0[s], pxh0[xs], acc00, 0, 0, 0);
            acc01 = __builtin_amdgcn_mfma_f32_32x32x16_bf16(qh0[s], pxh1[xs], acc01, 0, 0, 0);
            acc10 = __builtin_amdgcn_mfma_f32_32x32x16_bf16(qh1[s], pxh0[xs], acc10, 0, 0, 0);
            acc11 = __builtin_amdgcn_mfma_f32_32x32x16_bf16(qh1[s], pxh1[xs], acc11, 0, 0, 0);
            acc00 = __builtin_amdgcn_mfma_f32_32x32x16_bf16(ql0[s], pxh0[xs], acc00, 0, 0, 0);
            acc01 = __builtin_amdgcn_mfma_f32_32x32x16_bf16(ql0[s], pxh1[xs], acc01, 0, 0, 0);
            acc10 = __builtin_amdgcn_mfma_f32_32x32x16_bf16(ql1[s], pxh0[xs], acc10, 0, 0, 0);
            acc11 = __builtin_amdgcn_mfma_f32_32x32x16_bf16(ql1[s], pxh1[xs], acc11, 0, 0, 0);
            acc00 = __builtin_amdgcn_mfma_f32_32x32x16_bf16(qh0[s], pxl0[xs], acc00, 0, 0, 0);
            acc01 = __builtin_amdgcn_mfma_f32_32x32x16_bf16(qh0[s], pxl1[xs], acc01, 0, 0, 0);
            acc10 = __builtin_amdgcn_mfma_f32_32x32x16_bf16(qh1[s], pxl0[xs], acc10, 0, 0, 0);
            acc11 = __builtin_amdgcn_mfma_f32_32x32x16_bf16(qh1[s], pxl1[xs], acc11, 0, 0, 0);
        }
        __syncthreads();   // all waves done reading X before overwrite

        // epilogue: ReLU + re-split + aligned b64 stores.
        // Lane holds point p = 32*bt + l31, n_out in 4-runs: base + 8*r4 + 4*lh
        #pragma unroll
        for (int mti = 0; mti < 2; ++mti) {
            #pragma unroll
            for (int bt = 0; bt < 2; ++bt) {
                const f32x16 av = (mti == 0) ? (bt == 0 ? acc00 : acc01)
                                             : (bt == 0 ? acc10 : acc11);
                const int p = 32 * bt + l31;
                #pragma unroll
                for (int r4 = 0; r4 < 4; ++r4) {
                    unsigned short h[4], lo2[4];
                    #pragma unroll
                    for (int q = 0; q < 4; ++q) {
                        float v = fmaxf(av[4 * r4 + q], 0.0f);
                        split_bf(v, h[q], lo2[q]);
                    }
                    const int nb = 64 * wv + 32 * mti + 8 * r4 + 4 * lh;
                    const int a = xaddr(p, nb);   // 8B aligned within one 16B chunk
                    uint2 ph, pl;
                    ph.x = (uint32_t)h[0] | ((uint32_t)h[1] << 16);
                    ph.y = (uint32_t)h[2] | ((uint32_t)h[3] << 16);
                    pl.x = (uint32_t)lo2[0] | ((uint32_t)lo2[1] << 16);
                    pl.y = (uint32_t)lo2[2] | ((uint32_t)lo2[3] << 16);
                    *(uint2*)(Xhi + a) = ph;
                    *(uint2*)(Xlo + a) = pl;
                }
            }
        }
        __syncthreads();
    }

    // ---- layer 6: 256 -> 1 (VALU). 4 threads per point, shuffle-reduce. ----
    {
        const int m = tid >> 2;
        const int cq = tid & 3;
        float s = 0.0f;
        #pragma unroll
        for (int g = 0; g < 8; ++g) {
            int nb = cq * 64 + g * 8;
            int a = xaddr(m, nb);
            const short8 hv = *(const short8*)(Xhi + a);
            const short8 lv = *(const short8*)(Xlo + a);
            const float* wp = W6 + nb;
            #pragma unroll
            for (int j = 0; j < 8; ++j) {
                float x = bf2f((unsigned short)hv[j]) + bf2f((unsigned short)lv[j]);
                s = fmaf(x, wp[j], s);
            }
        }
        s += __shfl_xor(s, 1);
        s += __shfl_xor(s, 2);
        if (cq == 0) out[m0 + m] = s + b6[0];
    }
}

extern "C" void kernel_launch(void* const* d_in, const int* in_sizes, int n_in,
                              void* d_out, int out_size, void* d_ws, size_t ws_size,
                              hipStream_t stream) {
    const float* coords = (const float*)d_in[0];
    const float* W1 = (const float*)d_in[1];
    const float* b1 = (const float*)d_in[2];
    const float* W2 = (const float*)d_in[3];
    const float* b2 = (const float*)d_in[4];
    const float* W3 = (const float*)d_in[5];
    const float* b3 = (const float*)d_in[6];
    const float* W4 = (const float*)d_in[7];
    const float* b4 = (const float*)d_in[8];
    const float* W5 = (const float*)d_in[9];
    const float* b5 = (const float*)d_in[10];
    const float* W6 = (const float*)d_in[11];
    const float* b6 = (const float*)d_in[12];
    float* out = (float*)d_out;

    unsigned short* whi = (unsigned short*)d_ws;    // 512 KB
    unsigned short* wlo = whi + WPLANE;             // 512 KB (ws total 1 MB)

    prep_weights<<<1024, 256, 0, stream>>>(W2, W3, W4, W5, whi, wlo);

    const int nblocks = out_size / MT;              // 8192
    mlp_fused<<<nblocks, 256, 0, stream>>>(coords, W1, b1, b2, b3, b4, b5,
                                           W6, b6, whi, wlo, out);
}